// Round 7
// baseline (594.557 us; speedup 1.0000x reference)
//
#include <hip/hip_runtime.h>
#include <hip/hip_cooperative_groups.h>
#include <math.h>

namespace cg = cooperative_groups;

#define N_NODES 50000
#define N_HEDGE 5000
#define N_EDGES 400000
#define NB 2
#define NC 64
#define NEG 0.2f
#define NROWS (N_NODES * NB)   // 100000

#define GEMM_TILES ((NROWS + 63) / 64)         // 1563
#define ALLOC_BLOCKS ((N_NODES + 255) / 256)   // 196
#define HEDGE_BLOCKS ((N_HEDGE + 3) / 4)       // 1250

__device__ __forceinline__ unsigned short f2bf(float f) {
    unsigned int u = __float_as_uint(f);
    unsigned int r = (u + 0x7FFFu + ((u >> 16) & 1u)) >> 16;   // RNE
    return (unsigned short)r;
}

__device__ __forceinline__ float lrelu_exp(float r) {
    r = (r >= 0.f) ? r : NEG * r;
    r = fmaxf(r, -80.f);          // denom stays > 0 even pathologically
    return __expf(r);
}

// ============================================================================
// MEGA-KERNEL: entire pipeline in one cooperative launch.
// Phases separated by grid.sync() — replaces 7 dispatch boundaries with 6
// in-kernel barriers. Evidence: 3 structurally different pipelines all
// plateaued at 204-213us; R0->R1 showed ~6us per removed dispatch.
// ============================================================================
__global__ __launch_bounds__(256, 4) void mega_kernel(
    const float* __restrict__ x, const float* __restrict__ W,
    const float* __restrict__ att,
    const int* __restrict__ node_idx, const int* __restrict__ hedge_idx,
    unsigned short* __restrict__ xwb, float* __restrict__ p1, float* __restrict__ p2,
    float* __restrict__ s2, float* __restrict__ mtab, float* __restrict__ den,
    int* __restrict__ estart, int* __restrict__ cnt, int* __restrict__ gcursor,
    int* __restrict__ base, int* __restrict__ hperm, float* __restrict__ out)
{
    cg::grid_group grid = cg::this_grid();
    __shared__ float xs[64 * 68];
    __shared__ float Ws[64 * 68];
    __shared__ int sm[256];
    __shared__ int bbase;

    const int t    = threadIdx.x;
    const int nb   = gridDim.x;
    const int gsz  = nb * 256;
    const int gtid = blockIdx.x * 256 + t;
    const int wid  = gtid >> 6;            // global wave id (256-thread blocks -> 4 waves)
    const int nwv  = gsz >> 6;
    const int lane = t & 63;
    const int bsel = lane >> 5;            // batch for channel 2*lane

    // ---------------- P0: zero cnt+gcursor (contiguous); estart binary search
    for (int i = gtid; i < N_NODES + 8; i += gsz) cnt[i] = 0;
    for (int i = gtid; i <= N_HEDGE; i += gsz) {
        int lo = 0, hi = N_EDGES;
        while (lo < hi) {
            int mid = (lo + hi) >> 1;
            if (hedge_idx[mid] < i) lo = mid + 1; else hi = mid;
        }
        estart[i] = lo;
    }
    grid.sync();

    // ---------------- P1: incidence count atomics + GEMM tiles
    for (int e = gtid; e < N_EDGES; e += gsz) atomicAdd(&cnt[node_idx[e]], 1);

    for (int tile = blockIdx.x; tile < GEMM_TILES; tile += nb) {
        int R = tile * 64;
#pragma unroll
        for (int i = 0; i < 4; i++) {
            int lin = t + 256 * i;
            int r = lin >> 4, c4 = lin & 15;
            float4 wv = ((const float4*)W)[lin];
            *(float4*)&Ws[r * 68 + c4 * 4] = wv;
            int g = R + r;
            float4 xv = make_float4(0.f, 0.f, 0.f, 0.f);
            if (g < NROWS) {
                int n = g >> 1, b = g & 1;
                xv = ((const float4*)(x + ((size_t)b * N_NODES + n) * NC))[c4];
            }
            *(float4*)&xs[r * 68 + c4 * 4] = xv;
        }
        __syncthreads();

        int tr = t >> 4, tc = t & 15;
        float acc[4][4];
#pragma unroll
        for (int i = 0; i < 4; i++)
#pragma unroll
            for (int j = 0; j < 4; j++) acc[i][j] = 0.f;

#pragma unroll 4
        for (int k4 = 0; k4 < 16; k4++) {
            float4 xv[4], wv[4];
#pragma unroll
            for (int i = 0; i < 4; i++)
                xv[i] = *(const float4*)&xs[(tr * 4 + i) * 68 + k4 * 4];
#pragma unroll
            for (int kk = 0; kk < 4; kk++)
                wv[kk] = *(const float4*)&Ws[(k4 * 4 + kk) * 68 + tc * 4];
#pragma unroll
            for (int i = 0; i < 4; i++) {
                acc[i][0] = fmaf(xv[i].x, wv[0].x, acc[i][0]);
                acc[i][1] = fmaf(xv[i].x, wv[0].y, acc[i][1]);
                acc[i][2] = fmaf(xv[i].x, wv[0].z, acc[i][2]);
                acc[i][3] = fmaf(xv[i].x, wv[0].w, acc[i][3]);
                acc[i][0] = fmaf(xv[i].y, wv[1].x, acc[i][0]);
                acc[i][1] = fmaf(xv[i].y, wv[1].y, acc[i][1]);
                acc[i][2] = fmaf(xv[i].y, wv[1].z, acc[i][2]);
                acc[i][3] = fmaf(xv[i].y, wv[1].w, acc[i][3]);
                acc[i][0] = fmaf(xv[i].z, wv[2].x, acc[i][0]);
                acc[i][1] = fmaf(xv[i].z, wv[2].y, acc[i][1]);
                acc[i][2] = fmaf(xv[i].z, wv[2].z, acc[i][2]);
                acc[i][3] = fmaf(xv[i].z, wv[2].w, acc[i][3]);
                acc[i][0] = fmaf(xv[i].w, wv[3].x, acc[i][0]);
                acc[i][1] = fmaf(xv[i].w, wv[3].y, acc[i][1]);
                acc[i][2] = fmaf(xv[i].w, wv[3].z, acc[i][2]);
                acc[i][3] = fmaf(xv[i].w, wv[3].w, acc[i][3]);
            }
        }

        float a1x = att[tc * 4], a1y = att[tc * 4 + 1], a1z = att[tc * 4 + 2], a1w = att[tc * 4 + 3];
        float a2x = att[64 + tc * 4], a2y = att[64 + tc * 4 + 1], a2z = att[64 + tc * 4 + 2], a2w = att[64 + tc * 4 + 3];
#pragma unroll
        for (int i = 0; i < 4; i++) {
            int g = R + tr * 4 + i;
            if (g < NROWS) {
                ushort4 bv;
                bv.x = f2bf(acc[i][0]); bv.y = f2bf(acc[i][1]);
                bv.z = f2bf(acc[i][2]); bv.w = f2bf(acc[i][3]);
                ((ushort4*)(xwb + (size_t)g * 64))[tc] = bv;
            }
            float v1 = acc[i][0] * a1x + acc[i][1] * a1y + acc[i][2] * a1z + acc[i][3] * a1w;
            float v2 = acc[i][0] * a2x + acc[i][1] * a2y + acc[i][2] * a2z + acc[i][3] * a2w;
#pragma unroll
            for (int off = 8; off >= 1; off >>= 1) {
                v1 += __shfl_xor(v1, off, 64);
                v2 += __shfl_xor(v2, off, 64);
            }
            if (tc == 0 && g < NROWS) { p1[g] = v1; p2[g] = v2; }
        }
        __syncthreads();   // protect LDS before next tile's staging writes
    }
    grid.sync();

    // ---------------- P2: segment-base allocator (scan) + per-hyperedge p2 sums
    for (int vb = blockIdx.x; vb < ALLOC_BLOCKS; vb += nb) {
        int i = vb * 256 + t;
        int v = (i < N_NODES) ? cnt[i] : 0;
        sm[t] = v;
        __syncthreads();
        for (int off = 1; off < 256; off <<= 1) {
            int tv = (t >= off) ? sm[t - off] : 0;
            __syncthreads();
            sm[t] += tv;
            __syncthreads();
        }
        if (t == 255) bbase = atomicAdd(gcursor, sm[255]);
        __syncthreads();
        if (i < N_NODES) base[i] = bbase + sm[t] - v;
        __syncthreads();
    }
    for (int h = wid; h < N_HEDGE; h += nwv) {
        int s = estart[h], e1 = estart[h + 1];
        float a0 = 0.f, a1 = 0.f;
        for (int e = s + lane; e < e1; e += 64) {
            int n = node_idx[e];
            float2 p = ((const float2*)p2)[n];
            a0 += p.x; a1 += p.y;
        }
#pragma unroll
        for (int off = 32; off >= 1; off >>= 1) {
            a0 += __shfl_xor(a0, off, 64);
            a1 += __shfl_xor(a1, off, 64);
        }
        if (lane == 0) { s2[h * 2] = a0; s2[h * 2 + 1] = a1; }
    }
    grid.sync();

    // ---------------- P3: scatter (minimal CSR build; 4B scattered payload only)
    for (int e = gtid; e < N_EDGES; e += gsz) {
        int n = node_idx[e];
        int p = atomicAdd(&base[n], 1);        // base doubles as cursor; end = start+cnt
        hperm[p] = hedge_idx[e];
    }
    grid.sync();

    // ---------------- P4: den (per-node exp sums over CSR segment; feeds m only)
    for (int n = gtid; n < N_NODES; n += gsz) {
        int e1 = base[n];
        int s = e1 - cnt[n];
        float2 pn = ((const float2*)p1)[n];
        const float2* s2v = (const float2*)s2;
        float a0 = 0.f, a1 = 0.f;
        int j = s;
        for (; j + 3 < e1; j += 4) {
            int h0 = hperm[j], h1 = hperm[j + 1], h2 = hperm[j + 2], h3 = hperm[j + 3];
            float2 v0 = s2v[h0], v1 = s2v[h1], v2 = s2v[h2], v3 = s2v[h3];
            a0 += lrelu_exp(pn.x + v0.x) + lrelu_exp(pn.x + v1.x)
                + lrelu_exp(pn.x + v2.x) + lrelu_exp(pn.x + v3.x);
            a1 += lrelu_exp(pn.y + v0.y) + lrelu_exp(pn.y + v1.y)
                + lrelu_exp(pn.y + v2.y) + lrelu_exp(pn.y + v3.y);
        }
        for (; j < e1; j++) {
            float2 v = s2v[hperm[j]];
            a0 += lrelu_exp(pn.x + v.x);
            a1 += lrelu_exp(pn.y + v.y);
        }
        ((float2*)den)[n] = make_float2(a0, a1);
    }
    grid.sync();

    // ---------------- P5: m — 1 wave per hyperedge (no LDS, no block barrier)
    {
        const float2* p1v = (const float2*)p1;
        const float2* dn2 = (const float2*)den;
        for (int h = wid; h < N_HEDGE; h += nwv) {
            int s = estart[h], e1 = estart[h + 1];
            float2 s2h = ((const float2*)s2)[h];
            float sb = bsel ? s2h.y : s2h.x;
            float ax = 0.f, ay = 0.f;
            int e = s;
            for (; e + 3 < e1; e += 4) {
                int n0 = node_idx[e],     n1 = node_idx[e + 1];
                int n2 = node_idx[e + 2], n3 = node_idx[e + 3];
                float2 q0 = p1v[n0], q1 = p1v[n1], q2 = p1v[n2], q3 = p1v[n3];
                float2 d0 = dn2[n0], d1 = dn2[n1], d2 = dn2[n2], d3 = dn2[n3];
                float a0 = lrelu_exp((bsel ? q0.y : q0.x) + sb) * __builtin_amdgcn_rcpf(bsel ? d0.y : d0.x);
                float a1 = lrelu_exp((bsel ? q1.y : q1.x) + sb) * __builtin_amdgcn_rcpf(bsel ? d1.y : d1.x);
                float a2 = lrelu_exp((bsel ? q2.y : q2.x) + sb) * __builtin_amdgcn_rcpf(bsel ? d2.y : d2.x);
                float a3 = lrelu_exp((bsel ? q3.y : q3.x) + sb) * __builtin_amdgcn_rcpf(bsel ? d3.y : d3.x);
                unsigned int u0 = *(const unsigned int*)&xwb[(size_t)n0 * 128 + 2 * lane];
                unsigned int u1 = *(const unsigned int*)&xwb[(size_t)n1 * 128 + 2 * lane];
                unsigned int u2 = *(const unsigned int*)&xwb[(size_t)n2 * 128 + 2 * lane];
                unsigned int u3 = *(const unsigned int*)&xwb[(size_t)n3 * 128 + 2 * lane];
                ax = fmaf(a0, __uint_as_float(u0 << 16), ax);
                ay = fmaf(a0, __uint_as_float(u0 & 0xffff0000u), ay);
                ax = fmaf(a1, __uint_as_float(u1 << 16), ax);
                ay = fmaf(a1, __uint_as_float(u1 & 0xffff0000u), ay);
                ax = fmaf(a2, __uint_as_float(u2 << 16), ax);
                ay = fmaf(a2, __uint_as_float(u2 & 0xffff0000u), ay);
                ax = fmaf(a3, __uint_as_float(u3 << 16), ax);
                ay = fmaf(a3, __uint_as_float(u3 & 0xffff0000u), ay);
            }
            for (; e < e1; e++) {
                int n = node_idx[e];
                float2 q = p1v[n];
                float2 dv = dn2[n];
                float a0 = lrelu_exp((bsel ? q.y : q.x) + sb) * __builtin_amdgcn_rcpf(bsel ? dv.y : dv.x);
                unsigned int u = *(const unsigned int*)&xwb[(size_t)n * 128 + 2 * lane];
                ax = fmaf(a0, __uint_as_float(u << 16), ax);
                ay = fmaf(a0, __uint_as_float(u & 0xffff0000u), ay);
            }
            int d = e1 - s;
            float binv = (d > 0) ? 1.0f / (float)d : 0.0f;
            ((float2*)(mtab + (size_t)h * 128))[lane] = make_float2(binv * ax, binv * ay);
        }
    }
    grid.sync();

    // ---------------- P6: out — 1 wave per node; den self-computed from own exps
    {
        const float2* s2v = (const float2*)s2;
        for (int n = wid; n < N_NODES; n += nwv) {
            int d = cnt[n];
            int e1 = base[n];
            int s = e1 - d;
            float pnb = p1[2 * n + bsel];
            float ax = 0.f, ay = 0.f, sden = 0.f;
            int j = s;
            for (; j + 3 < e1; j += 4) {
                int h0 = hperm[j],     h1 = hperm[j + 1];
                int h2 = hperm[j + 2], h3 = hperm[j + 3];
                float2 w0 = s2v[h0], w1 = s2v[h1], w2 = s2v[h2], w3 = s2v[h3];
                float a0 = lrelu_exp(pnb + (bsel ? w0.y : w0.x));
                float a1 = lrelu_exp(pnb + (bsel ? w1.y : w1.x));
                float a2 = lrelu_exp(pnb + (bsel ? w2.y : w2.x));
                float a3 = lrelu_exp(pnb + (bsel ? w3.y : w3.x));
                float2 v0 = ((const float2*)(mtab + (size_t)h0 * 128))[lane];
                float2 v1 = ((const float2*)(mtab + (size_t)h1 * 128))[lane];
                float2 v2 = ((const float2*)(mtab + (size_t)h2 * 128))[lane];
                float2 v3 = ((const float2*)(mtab + (size_t)h3 * 128))[lane];
                ax = fmaf(a0, v0.x, ax); ay = fmaf(a0, v0.y, ay);
                ax = fmaf(a1, v1.x, ax); ay = fmaf(a1, v1.y, ay);
                ax = fmaf(a2, v2.x, ax); ay = fmaf(a2, v2.y, ay);
                ax = fmaf(a3, v3.x, ax); ay = fmaf(a3, v3.y, ay);
                sden += ((a0 + a1) + a2) + a3;
            }
            for (; j < e1; j++) {
                int h = hperm[j];
                float2 w0 = s2v[h];
                float a0 = lrelu_exp(pnb + (bsel ? w0.y : w0.x));
                float2 v = ((const float2*)(mtab + (size_t)h * 128))[lane];
                ax = fmaf(a0, v.x, ax); ay = fmaf(a0, v.y, ay);
                sden += a0;
            }
            float scale = (d > 0) ? (float)d * __builtin_amdgcn_rcpf(sden) : 0.f;
            int c = (2 * lane) & 63;
            float* dst = out + (size_t)bsel * N_NODES * 64 + (size_t)n * 64 + c;
            __builtin_nontemporal_store(scale * ax, &dst[0]);
            __builtin_nontemporal_store(scale * ay, &dst[1]);
        }
    }
}

// ============================================================================
// FALLBACK: proven R6 6-kernel pipeline (used only if cooperative launch fails)
// ============================================================================
__global__ __launch_bounds__(256, 4) void gemm_kernel(const float* __restrict__ x,
                                                      const float* __restrict__ W,
                                                      const float* __restrict__ att,
                                                      const int* __restrict__ node_idx,
                                                      const int* __restrict__ hedge_idx,
                                                      unsigned short* __restrict__ xwb,
                                                      float* __restrict__ p1,
                                                      float* __restrict__ p2,
                                                      int* __restrict__ cnt,
                                                      int* __restrict__ estart)
{
    __shared__ float xs[64 * 68];
    __shared__ float Ws[64 * 68];
    int t = threadIdx.x;
    int R = blockIdx.x * 64;

    int gid = blockIdx.x * 256 + t;
    if (gid < N_EDGES) atomicAdd(&cnt[node_idx[gid]], 1);
    if (gid <= N_HEDGE) {
        int lo = 0, hi = N_EDGES;
        while (lo < hi) {
            int mid = (lo + hi) >> 1;
            if (hedge_idx[mid] < gid) lo = mid + 1; else hi = mid;
        }
        estart[gid] = lo;
    }

#pragma unroll
    for (int i = 0; i < 4; i++) {
        int lin = t + 256 * i;
        int r = lin >> 4, c4 = lin & 15;
        float4 wv = ((const float4*)W)[lin];
        *(float4*)&Ws[r * 68 + c4 * 4] = wv;
        int g = R + r;
        float4 xv = make_float4(0.f, 0.f, 0.f, 0.f);
        if (g < NROWS) {
            int n = g >> 1, b = g & 1;
            xv = ((const float4*)(x + ((size_t)b * N_NODES + n) * NC))[c4];
        }
        *(float4*)&xs[r * 68 + c4 * 4] = xv;
    }
    __syncthreads();

    int tr = t >> 4, tc = t & 15;
    float acc[4][4];
#pragma unroll
    for (int i = 0; i < 4; i++)
#pragma unroll
        for (int j = 0; j < 4; j++) acc[i][j] = 0.f;

#pragma unroll 4
    for (int k4 = 0; k4 < 16; k4++) {
        float4 xv[4], wv[4];
#pragma unroll
        for (int i = 0; i < 4; i++)
            xv[i] = *(const float4*)&xs[(tr * 4 + i) * 68 + k4 * 4];
#pragma unroll
        for (int kk = 0; kk < 4; kk++)
            wv[kk] = *(const float4*)&Ws[(k4 * 4 + kk) * 68 + tc * 4];
#pragma unroll
        for (int i = 0; i < 4; i++) {
            acc[i][0] = fmaf(xv[i].x, wv[0].x, acc[i][0]);
            acc[i][1] = fmaf(xv[i].x, wv[0].y, acc[i][1]);
            acc[i][2] = fmaf(xv[i].x, wv[0].z, acc[i][2]);
            acc[i][3] = fmaf(xv[i].x, wv[0].w, acc[i][3]);
            acc[i][0] = fmaf(xv[i].y, wv[1].x, acc[i][0]);
            acc[i][1] = fmaf(xv[i].y, wv[1].y, acc[i][1]);
            acc[i][2] = fmaf(xv[i].y, wv[1].z, acc[i][2]);
            acc[i][3] = fmaf(xv[i].y, wv[1].w, acc[i][3]);
            acc[i][0] = fmaf(xv[i].z, wv[2].x, acc[i][0]);
            acc[i][1] = fmaf(xv[i].z, wv[2].y, acc[i][1]);
            acc[i][2] = fmaf(xv[i].z, wv[2].z, acc[i][2]);
            acc[i][3] = fmaf(xv[i].z, wv[2].w, acc[i][3]);
            acc[i][0] = fmaf(xv[i].w, wv[3].x, acc[i][0]);
            acc[i][1] = fmaf(xv[i].w, wv[3].y, acc[i][1]);
            acc[i][2] = fmaf(xv[i].w, wv[3].z, acc[i][2]);
            acc[i][3] = fmaf(xv[i].w, wv[3].w, acc[i][3]);
        }
    }

    float a1x = att[tc * 4], a1y = att[tc * 4 + 1], a1z = att[tc * 4 + 2], a1w = att[tc * 4 + 3];
    float a2x = att[64 + tc * 4], a2y = att[64 + tc * 4 + 1], a2z = att[64 + tc * 4 + 2], a2w = att[64 + tc * 4 + 3];
#pragma unroll
    for (int i = 0; i < 4; i++) {
        int g = R + tr * 4 + i;
        if (g < NROWS) {
            ushort4 bv;
            bv.x = f2bf(acc[i][0]); bv.y = f2bf(acc[i][1]);
            bv.z = f2bf(acc[i][2]); bv.w = f2bf(acc[i][3]);
            ((ushort4*)(xwb + (size_t)g * 64))[tc] = bv;
        }
        float v1 = acc[i][0] * a1x + acc[i][1] * a1y + acc[i][2] * a1z + acc[i][3] * a1w;
        float v2 = acc[i][0] * a2x + acc[i][1] * a2y + acc[i][2] * a2z + acc[i][3] * a2w;
#pragma unroll
        for (int off = 8; off >= 1; off >>= 1) {
            v1 += __shfl_xor(v1, off, 64);
            v2 += __shfl_xor(v2, off, 64);
        }
        if (tc == 0 && g < NROWS) { p1[g] = v1; p2[g] = v2; }
    }
}

__global__ __launch_bounds__(256) void ah_kernel(const int* __restrict__ cnt,
                                                 int* __restrict__ base,
                                                 int* __restrict__ gcursor,
                                                 const float* __restrict__ p2,
                                                 const int* __restrict__ node_idx,
                                                 const int* __restrict__ estart,
                                                 float* __restrict__ s2)
{
    if (blockIdx.x < ALLOC_BLOCKS) {
        __shared__ int sm[256];
        __shared__ int bbase;
        int tid = threadIdx.x;
        int i = blockIdx.x * 256 + tid;
        int v = (i < N_NODES) ? cnt[i] : 0;
        sm[tid] = v;
        __syncthreads();
        for (int off = 1; off < 256; off <<= 1) {
            int t2 = (tid >= off) ? sm[tid - off] : 0;
            __syncthreads();
            sm[tid] += t2;
            __syncthreads();
        }
        if (tid == 255) bbase = atomicAdd(gcursor, sm[255]);
        __syncthreads();
        if (i < N_NODES) base[i] = bbase + sm[tid] - v;
    } else {
        int wv = (blockIdx.x - ALLOC_BLOCKS) * 4 + (threadIdx.x >> 6);
        if (wv >= N_HEDGE) return;
        int lane = threadIdx.x & 63;
        int s = estart[wv], e1 = estart[wv + 1];
        float a0 = 0.f, a1 = 0.f;
        for (int e = s + lane; e < e1; e += 64) {
            int n = node_idx[e];
            float2 p = ((const float2*)p2)[n];
            a0 += p.x; a1 += p.y;
        }
#pragma unroll
        for (int off = 32; off >= 1; off >>= 1) {
            a0 += __shfl_xor(a0, off, 64);
            a1 += __shfl_xor(a1, off, 64);
        }
        if (lane == 0) { s2[wv * 2] = a0; s2[wv * 2 + 1] = a1; }
    }
}

__global__ __launch_bounds__(256) void scatter_kernel(const int* __restrict__ node_idx,
                                                      const int* __restrict__ hedge_idx,
                                                      int* __restrict__ base,
                                                      int* __restrict__ hperm)
{
    int e = blockIdx.x * 256 + threadIdx.x;
    if (e >= N_EDGES) return;
    int n = node_idx[e];
    int h = hedge_idx[e];
    int p = atomicAdd(&base[n], 1);
    hperm[p] = h;
}

__global__ __launch_bounds__(256) void den_kernel(const int* __restrict__ base,
                                                  const int* __restrict__ cnt,
                                                  const int* __restrict__ hperm,
                                                  const float* __restrict__ p1,
                                                  const float* __restrict__ s2,
                                                  float* __restrict__ den)
{
    int n = blockIdx.x * 256 + threadIdx.x;
    if (n >= N_NODES) return;
    int e1 = base[n];
    int s = e1 - cnt[n];
    float2 pn = ((const float2*)p1)[n];
    const float2* s2v = (const float2*)s2;
    float a0 = 0.f, a1 = 0.f;
    int j = s;
    for (; j + 3 < e1; j += 4) {
        int h0 = hperm[j], h1 = hperm[j + 1], h2 = hperm[j + 2], h3 = hperm[j + 3];
        float2 v0 = s2v[h0], v1 = s2v[h1], v2 = s2v[h2], v3 = s2v[h3];
        a0 += lrelu_exp(pn.x + v0.x) + lrelu_exp(pn.x + v1.x)
            + lrelu_exp(pn.x + v2.x) + lrelu_exp(pn.x + v3.x);
        a1 += lrelu_exp(pn.y + v0.y) + lrelu_exp(pn.y + v1.y)
            + lrelu_exp(pn.y + v2.y) + lrelu_exp(pn.y + v3.y);
    }
    for (; j < e1; j++) {
        float2 v = s2v[hperm[j]];
        a0 += lrelu_exp(pn.x + v.x);
        a1 += lrelu_exp(pn.y + v.y);
    }
    ((float2*)den)[n] = make_float2(a0, a1);
}

__global__ __launch_bounds__(128) void m_kernel(const unsigned short* __restrict__ xwb,
                                                const int* __restrict__ node_idx,
                                                const int* __restrict__ estart,
                                                const float* __restrict__ p1,
                                                const float* __restrict__ s2,
                                                const float* __restrict__ den,
                                                float* __restrict__ m)
{
    __shared__ float red[128];
    int h = blockIdx.x;
    int t = threadIdx.x;
    int w = t >> 6, l = t & 63;
    int b = l >> 5;
    int s = estart[h], e1 = estart[h + 1];
    float2 s2h = ((const float2*)s2)[h];
    float sb = b ? s2h.y : s2h.x;
    const float2* p1v = (const float2*)p1;
    const float2* dn2 = (const float2*)den;
    float ax = 0.f, ay = 0.f;
    int e = s + w;
    for (; e + 6 < e1; e += 8) {
        int n0 = node_idx[e],     n1 = node_idx[e + 2];
        int n2 = node_idx[e + 4], n3 = node_idx[e + 6];
        float2 q0 = p1v[n0], q1 = p1v[n1], q2 = p1v[n2], q3 = p1v[n3];
        float2 d0 = dn2[n0], d1 = dn2[n1], d2 = dn2[n2], d3 = dn2[n3];
        float a0 = lrelu_exp((b ? q0.y : q0.x) + sb) * __builtin_amdgcn_rcpf(b ? d0.y : d0.x);
        float a1 = lrelu_exp((b ? q1.y : q1.x) + sb) * __builtin_amdgcn_rcpf(b ? d1.y : d1.x);
        float a2 = lrelu_exp((b ? q2.y : q2.x) + sb) * __builtin_amdgcn_rcpf(b ? d2.y : d2.x);
        float a3 = lrelu_exp((b ? q3.y : q3.x) + sb) * __builtin_amdgcn_rcpf(b ? d3.y : d3.x);
        unsigned int u0 = *(const unsigned int*)&xwb[(size_t)n0 * 128 + 2 * l];
        unsigned int u1 = *(const unsigned int*)&xwb[(size_t)n1 * 128 + 2 * l];
        unsigned int u2 = *(const unsigned int*)&xwb[(size_t)n2 * 128 + 2 * l];
        unsigned int u3 = *(const unsigned int*)&xwb[(size_t)n3 * 128 + 2 * l];
        ax = fmaf(a0, __uint_as_float(u0 << 16), ax);
        ay = fmaf(a0, __uint_as_float(u0 & 0xffff0000u), ay);
        ax = fmaf(a1, __uint_as_float(u1 << 16), ax);
        ay = fmaf(a1, __uint_as_float(u1 & 0xffff0000u), ay);
        ax = fmaf(a2, __uint_as_float(u2 << 16), ax);
        ay = fmaf(a2, __uint_as_float(u2 & 0xffff0000u), ay);
        ax = fmaf(a3, __uint_as_float(u3 << 16), ax);
        ay = fmaf(a3, __uint_as_float(u3 & 0xffff0000u), ay);
    }
    for (; e < e1; e += 2) {
        int n = node_idx[e];
        float2 q = p1v[n];
        float2 dv = dn2[n];
        float a0 = lrelu_exp((b ? q.y : q.x) + sb) * __builtin_amdgcn_rcpf(b ? dv.y : dv.x);
        unsigned int u = *(const unsigned int*)&xwb[(size_t)n * 128 + 2 * l];
        ax = fmaf(a0, __uint_as_float(u << 16), ax);
        ay = fmaf(a0, __uint_as_float(u & 0xffff0000u), ay);
    }
    if (w == 1) { red[2 * l] = ax; red[2 * l + 1] = ay; }
    __syncthreads();
    if (w == 0) {
        ax += red[2 * l]; ay += red[2 * l + 1];
        int d = e1 - s;
        float binv = (d > 0) ? 1.0f / (float)d : 0.0f;
        ((float2*)(m + (size_t)h * 128))[l] = make_float2(binv * ax, binv * ay);
    }
}

__global__ __launch_bounds__(256) void out_kernel(const float* __restrict__ m,
                                                  const int* __restrict__ hperm,
                                                  const float* __restrict__ p1,
                                                  const float* __restrict__ s2,
                                                  const int* __restrict__ base,
                                                  const int* __restrict__ cnt,
                                                  const float* __restrict__ den,
                                                  float* __restrict__ out)
{
    int n = blockIdx.x * 4 + (threadIdx.x >> 6);
    if (n >= N_NODES) return;
    int l = threadIdx.x & 63;
    int b = l >> 5;
    int d = cnt[n];
    int e1 = base[n];
    int s = e1 - d;
    float pnb = p1[2 * n + b];
    const float2* s2v = (const float2*)s2;
    float ax = 0.f, ay = 0.f;
    int j = s;
    for (; j + 3 < e1; j += 4) {
        int h0 = hperm[j],     h1 = hperm[j + 1];
        int h2 = hperm[j + 2], h3 = hperm[j + 3];
        float2 w0 = s2v[h0], w1 = s2v[h1], w2 = s2v[h2], w3 = s2v[h3];
        float a0 = lrelu_exp(pnb + (b ? w0.y : w0.x));
        float a1 = lrelu_exp(pnb + (b ? w1.y : w1.x));
        float a2 = lrelu_exp(pnb + (b ? w2.y : w2.x));
        float a3 = lrelu_exp(pnb + (b ? w3.y : w3.x));
        float2 v0 = ((const float2*)(m + (size_t)h0 * 128))[l];
        float2 v1 = ((const float2*)(m + (size_t)h1 * 128))[l];
        float2 v2 = ((const float2*)(m + (size_t)h2 * 128))[l];
        float2 v3 = ((const float2*)(m + (size_t)h3 * 128))[l];
        ax = fmaf(a0, v0.x, ax); ay = fmaf(a0, v0.y, ay);
        ax = fmaf(a1, v1.x, ax); ay = fmaf(a1, v1.y, ay);
        ax = fmaf(a2, v2.x, ax); ay = fmaf(a2, v2.y, ay);
        ax = fmaf(a3, v3.x, ax); ay = fmaf(a3, v3.y, ay);
    }
    for (; j < e1; j++) {
        int h = hperm[j];
        float2 w0 = s2v[h];
        float a0 = lrelu_exp(pnb + (b ? w0.y : w0.x));
        float2 v = ((const float2*)(m + (size_t)h * 128))[l];
        ax = fmaf(a0, v.x, ax); ay = fmaf(a0, v.y, ay);
    }
    float dd = den[2 * n + b];
    float scale = (d > 0) ? (float)d * __builtin_amdgcn_rcpf(dd) : 0.f;
    int c = (2 * l) & 63;
    float* dst = out + (size_t)b * N_NODES * 64 + (size_t)n * 64 + c;
    __builtin_nontemporal_store(scale * ax, &dst[0]);
    __builtin_nontemporal_store(scale * ay, &dst[1]);
}

extern "C" void kernel_launch(void* const* d_in, const int* in_sizes, int n_in,
                              void* d_out, int out_size, void* d_ws, size_t ws_size,
                              hipStream_t stream)
{
    const float* x      = (const float*)d_in[0];
    const float* W      = (const float*)d_in[1];
    const float* att    = (const float*)d_in[2];
    const int* node_idx = (const int*)d_in[3];
    const int* hedge_idx= (const int*)d_in[4];
    float* out = (float*)d_out;

    // workspace layout — ~21MB total
    unsigned short* xwb = (unsigned short*)d_ws;        // 6,400,000 ushort (12.8MB)
    float* p1     = (float*)(xwb + (size_t)NROWS * NC); // 100,000
    float* p2     = p1 + NROWS;                         // 100,000
    float* s2     = p2 + NROWS;                         // 10,000
    float* m      = s2 + 10000;                         // 640,000
    float* den    = m + (size_t)N_HEDGE * NB * NC;      // 100,000
    int* estart  = (int*)(den + NROWS);                 // 5,008 (padded)
    int* cnt     = estart + 5008;                       // 50,000 ┐ contiguous (zeroed in P0)
    int* gcursor = cnt + N_NODES;                       // 8      ┘
    int* base    = gcursor + 8;                         // 50,000
    int* hperm   = base + N_NODES;                      // 400,000

    // co-resident grid for cooperative launch (static-cached occupancy query)
    static int nblk = 0;
    if (nblk == 0) {
        int per_cu = 0;
        if (hipOccupancyMaxActiveBlocksPerMultiprocessor(&per_cu, mega_kernel, 256, 0) != hipSuccess
            || per_cu <= 0)
            per_cu = 2;                     // conservative fallback (LDS 35.9KB -> >=4 fits)
        if (per_cu > 4) per_cu = 4;
        nblk = per_cu * 256;                // 256 CUs on MI355X
    }

    void* args[] = { (void*)&x, (void*)&W, (void*)&att, (void*)&node_idx, (void*)&hedge_idx,
                     (void*)&xwb, (void*)&p1, (void*)&p2, (void*)&s2, (void*)&m, (void*)&den,
                     (void*)&estart, (void*)&cnt, (void*)&gcursor, (void*)&base, (void*)&hperm,
                     (void*)&out };
    hipError_t err = hipLaunchCooperativeKernel((const void*)mega_kernel,
                                                dim3(nblk), dim3(256), args, 0, stream);
    if (err != hipSuccess) {
        // fallback: proven R6 multi-kernel pipeline
        (void)hipGetLastError();
        hipMemsetAsync(cnt, 0, (size_t)(N_NODES + 8) * sizeof(int), stream);
        gemm_kernel<<<(NROWS + 63) / 64, 256, 0, stream>>>(x, W, att, node_idx, hedge_idx,
                                                           xwb, p1, p2, cnt, estart);
        ah_kernel<<<ALLOC_BLOCKS + HEDGE_BLOCKS, 256, 0, stream>>>(cnt, base, gcursor,
                                                                   p2, node_idx, estart, s2);
        scatter_kernel<<<(N_EDGES + 255) / 256, 256, 0, stream>>>(node_idx, hedge_idx,
                                                                  base, hperm);
        den_kernel<<<(N_NODES + 255) / 256, 256, 0, stream>>>(base, cnt, hperm, p1, s2, den);
        m_kernel<<<N_HEDGE, 128, 0, stream>>>(xwb, node_idx, estart, p1, s2, den, m);
        out_kernel<<<(N_NODES + 3) / 4, 256, 0, stream>>>(m, hperm, p1, s2, base, cnt, den, out);
    }
}

// Round 8
// 202.467 us; speedup vs baseline: 2.9366x; 2.9366x over previous
//
#include <hip/hip_runtime.h>
#include <math.h>

#define N_NODES 50000
#define N_HEDGE 5000
#define N_EDGES 400000
#define NB 2
#define NC 64
#define NEG 0.2f
#define NROWS (N_NODES * NB)   // 100000

#define ALLOC_BLOCKS ((N_NODES + 255) / 256)   // 196
#define HEDGE_BLOCKS ((N_HEDGE + 3) / 4)       // 1250

__device__ __forceinline__ unsigned short f2bf(float f) {
    unsigned int u = __float_as_uint(f);
    unsigned int r = (u + 0x7FFFu + ((u >> 16) & 1u)) >> 16;   // RNE
    return (unsigned short)r;
}

__device__ __forceinline__ float lrelu_exp(float r) {
    r = (r >= 0.f) ? r : NEG * r;
    r = fmaxf(r, -80.f);          // denom stays > 0 even pathologically
    return __expf(r);
}

// ---------------- GEMM: xw[row][c] bf16, row = n*2+b; epilogue p1/p2
// fused: incidence count — the atomicAdd return value IS the edge's rank
// within its node's CSR segment (stored to rank[], makes scatter atomic-free)
// + estart binary search.
__global__ __launch_bounds__(256, 4) void gemm_kernel(const float* __restrict__ x,
                                                      const float* __restrict__ W,
                                                      const float* __restrict__ att,
                                                      const int* __restrict__ node_idx,
                                                      const int* __restrict__ hedge_idx,
                                                      unsigned short* __restrict__ xwb,
                                                      float* __restrict__ p1,
                                                      float* __restrict__ p2,
                                                      int* __restrict__ cnt,
                                                      int* __restrict__ rank,
                                                      int* __restrict__ estart)
{
    __shared__ float xs[64 * 68];
    __shared__ float Ws[64 * 68];
    int t = threadIdx.x;
    int R = blockIdx.x * 64;

    // fused count work (grid 1563*256 = 400128 >= N_EDGES, >= N_HEDGE+1)
    int gid = blockIdx.x * 256 + t;
    if (gid < N_EDGES) {
        rank[gid] = atomicAdd(&cnt[node_idx[gid]], 1);
    }
    if (gid <= N_HEDGE) {
        int lo = 0, hi = N_EDGES;
        while (lo < hi) {
            int mid = (lo + hi) >> 1;
            if (hedge_idx[mid] < gid) lo = mid + 1; else hi = mid;
        }
        estart[gid] = lo;
    }

#pragma unroll
    for (int i = 0; i < 4; i++) {
        int lin = t + 256 * i;
        int r = lin >> 4, c4 = lin & 15;
        float4 wv = ((const float4*)W)[lin];
        *(float4*)&Ws[r * 68 + c4 * 4] = wv;
        int g = R + r;
        float4 xv = make_float4(0.f, 0.f, 0.f, 0.f);
        if (g < NROWS) {
            int n = g >> 1, b = g & 1;
            xv = ((const float4*)(x + ((size_t)b * N_NODES + n) * NC))[c4];
        }
        *(float4*)&xs[r * 68 + c4 * 4] = xv;
    }
    __syncthreads();

    int tr = t >> 4, tc = t & 15;
    float acc[4][4];
#pragma unroll
    for (int i = 0; i < 4; i++)
#pragma unroll
        for (int j = 0; j < 4; j++) acc[i][j] = 0.f;

#pragma unroll 4
    for (int k4 = 0; k4 < 16; k4++) {
        float4 xv[4], wv[4];
#pragma unroll
        for (int i = 0; i < 4; i++)
            xv[i] = *(const float4*)&xs[(tr * 4 + i) * 68 + k4 * 4];
#pragma unroll
        for (int kk = 0; kk < 4; kk++)
            wv[kk] = *(const float4*)&Ws[(k4 * 4 + kk) * 68 + tc * 4];
#pragma unroll
        for (int i = 0; i < 4; i++) {
            acc[i][0] = fmaf(xv[i].x, wv[0].x, acc[i][0]);
            acc[i][1] = fmaf(xv[i].x, wv[0].y, acc[i][1]);
            acc[i][2] = fmaf(xv[i].x, wv[0].z, acc[i][2]);
            acc[i][3] = fmaf(xv[i].x, wv[0].w, acc[i][3]);
            acc[i][0] = fmaf(xv[i].y, wv[1].x, acc[i][0]);
            acc[i][1] = fmaf(xv[i].y, wv[1].y, acc[i][1]);
            acc[i][2] = fmaf(xv[i].y, wv[1].z, acc[i][2]);
            acc[i][3] = fmaf(xv[i].y, wv[1].w, acc[i][3]);
            acc[i][0] = fmaf(xv[i].z, wv[2].x, acc[i][0]);
            acc[i][1] = fmaf(xv[i].z, wv[2].y, acc[i][1]);
            acc[i][2] = fmaf(xv[i].z, wv[2].z, acc[i][2]);
            acc[i][3] = fmaf(xv[i].z, wv[2].w, acc[i][3]);
            acc[i][0] = fmaf(xv[i].w, wv[3].x, acc[i][0]);
            acc[i][1] = fmaf(xv[i].w, wv[3].y, acc[i][1]);
            acc[i][2] = fmaf(xv[i].w, wv[3].z, acc[i][2]);
            acc[i][3] = fmaf(xv[i].w, wv[3].w, acc[i][3]);
        }
    }

    float a1x = att[tc * 4], a1y = att[tc * 4 + 1], a1z = att[tc * 4 + 2], a1w = att[tc * 4 + 3];
    float a2x = att[64 + tc * 4], a2y = att[64 + tc * 4 + 1], a2z = att[64 + tc * 4 + 2], a2w = att[64 + tc * 4 + 3];
#pragma unroll
    for (int i = 0; i < 4; i++) {
        int g = R + tr * 4 + i;
        if (g < NROWS) {
            ushort4 bv;
            bv.x = f2bf(acc[i][0]); bv.y = f2bf(acc[i][1]);
            bv.z = f2bf(acc[i][2]); bv.w = f2bf(acc[i][3]);
            ((ushort4*)(xwb + (size_t)g * 64))[tc] = bv;
        }
        float v1 = acc[i][0] * a1x + acc[i][1] * a1y + acc[i][2] * a1z + acc[i][3] * a1w;
        float v2 = acc[i][0] * a2x + acc[i][1] * a2y + acc[i][2] * a2z + acc[i][3] * a2w;
#pragma unroll
        for (int off = 8; off >= 1; off >>= 1) {
            v1 += __shfl_xor(v1, off, 64);
            v2 += __shfl_xor(v2, off, 64);
        }
        if (tc == 0 && g < NROWS) { p1[g] = v1; p2[g] = v2; }
    }
}

// ---------------- fused: segment-base allocator + per-hyperedge p2 sums
// base[n] = segment START (never bumped — scatter is atomic-free via rank[]).
__global__ __launch_bounds__(256) void ah_kernel(const int* __restrict__ cnt,
                                                 int* __restrict__ base,
                                                 int* __restrict__ gcursor,
                                                 const float* __restrict__ p2,
                                                 const int* __restrict__ node_idx,
                                                 const int* __restrict__ estart,
                                                 float* __restrict__ s2)
{
    if (blockIdx.x < ALLOC_BLOCKS) {
        __shared__ int sm[256];
        __shared__ int bbase;
        int tid = threadIdx.x;
        int i = blockIdx.x * 256 + tid;
        int v = (i < N_NODES) ? cnt[i] : 0;
        sm[tid] = v;
        __syncthreads();
        for (int off = 1; off < 256; off <<= 1) {
            int t2 = (tid >= off) ? sm[tid - off] : 0;
            __syncthreads();
            sm[tid] += t2;
            __syncthreads();
        }
        if (tid == 255) bbase = atomicAdd(gcursor, sm[255]);
        __syncthreads();
        if (i < N_NODES) base[i] = bbase + sm[tid] - v;
    } else {
        int wv = (blockIdx.x - ALLOC_BLOCKS) * 4 + (threadIdx.x >> 6);
        if (wv >= N_HEDGE) return;
        int lane = threadIdx.x & 63;
        int s = estart[wv], e1 = estart[wv + 1];
        float a0 = 0.f, a1 = 0.f;
        for (int e = s + lane; e < e1; e += 64) {
            int n = node_idx[e];
            float2 p = ((const float2*)p2)[n];
            a0 += p.x; a1 += p.y;
        }
#pragma unroll
        for (int off = 32; off >= 1; off >>= 1) {
            a0 += __shfl_xor(a0, off, 64);
            a1 += __shfl_xor(a1, off, 64);
        }
        if (lane == 0) { s2[wv * 2] = a0; s2[wv * 2 + 1] = a1; }
    }
}

// ---------------- scatter: atomic-free CSR build.
// 3 coalesced reads + 1 base gather + 1 scattered 4B store. The atomic
// round-trip of the old cursor-bump is gone (rank precomputed in gemm).
__global__ __launch_bounds__(256) void scatter_kernel(const int* __restrict__ node_idx,
                                                      const int* __restrict__ hedge_idx,
                                                      const int* __restrict__ rank,
                                                      const int* __restrict__ base,
                                                      int* __restrict__ hperm)
{
    int e = blockIdx.x * 256 + threadIdx.x;
    if (e >= N_EDGES) return;
    int n = node_idx[e];
    hperm[base[n] + rank[e]] = hedge_idx[e];
}

// ---------------- den: per-node (both batches) sum of exp over the CSR segment.
__global__ __launch_bounds__(256) void den_kernel(const int* __restrict__ base,
                                                  const int* __restrict__ cnt,
                                                  const int* __restrict__ hperm,
                                                  const float* __restrict__ p1,
                                                  const float* __restrict__ s2,
                                                  float* __restrict__ den)
{
    int n = blockIdx.x * 256 + threadIdx.x;
    if (n >= N_NODES) return;
    int s = base[n];
    int e1 = s + cnt[n];
    float2 pn = ((const float2*)p1)[n];
    const float2* s2v = (const float2*)s2;
    float a0 = 0.f, a1 = 0.f;
    int j = s;
    for (; j + 3 < e1; j += 4) {   // 4 independent gather chains
        int h0 = hperm[j], h1 = hperm[j + 1], h2 = hperm[j + 2], h3 = hperm[j + 3];
        float2 v0 = s2v[h0], v1 = s2v[h1], v2 = s2v[h2], v3 = s2v[h3];
        a0 += lrelu_exp(pn.x + v0.x) + lrelu_exp(pn.x + v1.x)
            + lrelu_exp(pn.x + v2.x) + lrelu_exp(pn.x + v3.x);
        a1 += lrelu_exp(pn.y + v0.y) + lrelu_exp(pn.y + v1.y)
            + lrelu_exp(pn.y + v2.y) + lrelu_exp(pn.y + v3.y);
    }
    for (; j < e1; j++) {
        float2 v = s2v[hperm[j]];
        a0 += lrelu_exp(pn.x + v.x);
        a1 += lrelu_exp(pn.y + v.y);
    }
    ((float2*)den)[n] = make_float2(a0, a1);
}

// ---------------- pass 1: m[h][k] = (1/deg_h) * sum_{e in h} (ev_e/den[n_e]) * xw[n_e][k]
// 1 wave per hyperedge, 4 per block — no LDS round-trip, no block barrier.
__global__ __launch_bounds__(256) void m_kernel(const unsigned short* __restrict__ xwb,
                                                const int* __restrict__ node_idx,
                                                const int* __restrict__ estart,
                                                const float* __restrict__ p1,
                                                const float* __restrict__ s2,
                                                const float* __restrict__ den,
                                                float* __restrict__ m)
{
    int h = blockIdx.x * 4 + (threadIdx.x >> 6);
    if (h >= N_HEDGE) return;
    int l = threadIdx.x & 63;
    int b = l >> 5;                       // channel 2l: b = (2l)>>6
    int s = estart[h], e1 = estart[h + 1];
    float2 s2h = ((const float2*)s2)[h];  // wave-uniform
    float sb = b ? s2h.y : s2h.x;
    const float2* p1v = (const float2*)p1;
    const float2* dn2 = (const float2*)den;
    float ax = 0.f, ay = 0.f;
    int e = s;
    for (; e + 3 < e1; e += 4) {
        int n0 = node_idx[e],     n1 = node_idx[e + 1];
        int n2 = node_idx[e + 2], n3 = node_idx[e + 3];
        float2 q0 = p1v[n0], q1 = p1v[n1], q2 = p1v[n2], q3 = p1v[n3];
        float2 d0 = dn2[n0], d1 = dn2[n1], d2 = dn2[n2], d3 = dn2[n3];
        float a0 = lrelu_exp((b ? q0.y : q0.x) + sb) * __builtin_amdgcn_rcpf(b ? d0.y : d0.x);
        float a1 = lrelu_exp((b ? q1.y : q1.x) + sb) * __builtin_amdgcn_rcpf(b ? d1.y : d1.x);
        float a2 = lrelu_exp((b ? q2.y : q2.x) + sb) * __builtin_amdgcn_rcpf(b ? d2.y : d2.x);
        float a3 = lrelu_exp((b ? q3.y : q3.x) + sb) * __builtin_amdgcn_rcpf(b ? d3.y : d3.x);
        unsigned int u0 = *(const unsigned int*)&xwb[(size_t)n0 * 128 + 2 * l];
        unsigned int u1 = *(const unsigned int*)&xwb[(size_t)n1 * 128 + 2 * l];
        unsigned int u2 = *(const unsigned int*)&xwb[(size_t)n2 * 128 + 2 * l];
        unsigned int u3 = *(const unsigned int*)&xwb[(size_t)n3 * 128 + 2 * l];
        ax = fmaf(a0, __uint_as_float(u0 << 16), ax);
        ay = fmaf(a0, __uint_as_float(u0 & 0xffff0000u), ay);
        ax = fmaf(a1, __uint_as_float(u1 << 16), ax);
        ay = fmaf(a1, __uint_as_float(u1 & 0xffff0000u), ay);
        ax = fmaf(a2, __uint_as_float(u2 << 16), ax);
        ay = fmaf(a2, __uint_as_float(u2 & 0xffff0000u), ay);
        ax = fmaf(a3, __uint_as_float(u3 << 16), ax);
        ay = fmaf(a3, __uint_as_float(u3 & 0xffff0000u), ay);
    }
    for (; e < e1; e++) {
        int n = node_idx[e];
        float2 q = p1v[n];
        float2 dv = dn2[n];
        float a0 = lrelu_exp((b ? q.y : q.x) + sb) * __builtin_amdgcn_rcpf(b ? dv.y : dv.x);
        unsigned int u = *(const unsigned int*)&xwb[(size_t)n * 128 + 2 * l];
        ax = fmaf(a0, __uint_as_float(u << 16), ax);
        ay = fmaf(a0, __uint_as_float(u & 0xffff0000u), ay);
    }
    int d = e1 - s;
    float binv = (d > 0) ? 1.0f / (float)d : 0.0f;
    ((float2*)(m + (size_t)h * 128))[l] = make_float2(binv * ax, binv * ay);
}

// ---------------- pass 2: out[b][n][c] = (deg/den[n]) * sum_j ev_j * m[h_j][k]
// 1 wave per node; ev recomputed inline (p1[2n+b] half-wave-uniform, s2[h]
// gather broadcasts within each half-wave).
__global__ __launch_bounds__(256) void out_kernel(const float* __restrict__ m,
                                                  const int* __restrict__ hperm,
                                                  const float* __restrict__ p1,
                                                  const float* __restrict__ s2,
                                                  const int* __restrict__ base,
                                                  const int* __restrict__ cnt,
                                                  const float* __restrict__ den,
                                                  float* __restrict__ out)
{
    int n = blockIdx.x * 4 + (threadIdx.x >> 6);
    if (n >= N_NODES) return;
    int l = threadIdx.x & 63;
    int b = l >> 5;
    int d = cnt[n];
    int s = base[n];
    int e1 = s + d;
    float pnb = p1[2 * n + b];
    const float2* s2v = (const float2*)s2;
    float ax = 0.f, ay = 0.f;
    int j = s;
    for (; j + 3 < e1; j += 4) {
        int h0 = hperm[j],     h1 = hperm[j + 1];
        int h2 = hperm[j + 2], h3 = hperm[j + 3];
        float2 w0 = s2v[h0], w1 = s2v[h1], w2 = s2v[h2], w3 = s2v[h3];
        float a0 = lrelu_exp(pnb + (b ? w0.y : w0.x));
        float a1 = lrelu_exp(pnb + (b ? w1.y : w1.x));
        float a2 = lrelu_exp(pnb + (b ? w2.y : w2.x));
        float a3 = lrelu_exp(pnb + (b ? w3.y : w3.x));
        float2 v0 = ((const float2*)(m + (size_t)h0 * 128))[l];
        float2 v1 = ((const float2*)(m + (size_t)h1 * 128))[l];
        float2 v2 = ((const float2*)(m + (size_t)h2 * 128))[l];
        float2 v3 = ((const float2*)(m + (size_t)h3 * 128))[l];
        ax = fmaf(a0, v0.x, ax); ay = fmaf(a0, v0.y, ay);
        ax = fmaf(a1, v1.x, ax); ay = fmaf(a1, v1.y, ay);
        ax = fmaf(a2, v2.x, ax); ay = fmaf(a2, v2.y, ay);
        ax = fmaf(a3, v3.x, ax); ay = fmaf(a3, v3.y, ay);
    }
    for (; j < e1; j++) {
        int h = hperm[j];
        float2 w0 = s2v[h];
        float a0 = lrelu_exp(pnb + (b ? w0.y : w0.x));
        float2 v = ((const float2*)(m + (size_t)h * 128))[l];
        ax = fmaf(a0, v.x, ax); ay = fmaf(a0, v.y, ay);
    }
    float dd = den[2 * n + b];
    // deg * (1/den); zero-degree nodes write exact 0 (ax=ay=0, scale=0)
    float scale = (d > 0) ? (float)d * __builtin_amdgcn_rcpf(dd) : 0.f;
    int c = (2 * l) & 63;
    float* dst = out + (size_t)b * N_NODES * 64 + (size_t)n * 64 + c;
    __builtin_nontemporal_store(scale * ax, &dst[0]);
    __builtin_nontemporal_store(scale * ay, &dst[1]);
}

extern "C" void kernel_launch(void* const* d_in, const int* in_sizes, int n_in,
                              void* d_out, int out_size, void* d_ws, size_t ws_size,
                              hipStream_t stream)
{
    const float* x      = (const float*)d_in[0];
    const float* W      = (const float*)d_in[1];
    const float* att    = (const float*)d_in[2];
    const int* node_idx = (const int*)d_in[3];
    const int* hedge_idx= (const int*)d_in[4];
    float* out = (float*)d_out;

    // workspace layout — ~23MB total
    unsigned short* xwb = (unsigned short*)d_ws;        // 6,400,000 ushort (12.8MB)
    float* p1     = (float*)(xwb + (size_t)NROWS * NC); // 100,000
    float* p2     = p1 + NROWS;                         // 100,000
    float* s2     = p2 + NROWS;                         // 10,000
    float* m      = s2 + 10000;                         // 640,000
    float* den    = m + (size_t)N_HEDGE * NB * NC;      // 100,000
    int* estart  = (int*)(den + NROWS);                 // 5,008 (padded)
    int* cnt     = estart + 5008;                       // 50,000 ┐ contiguous memset
    int* gcursor = cnt + N_NODES;                       // 8      ┘
    int* base    = gcursor + 8;                         // 50,000
    int* hperm   = base + N_NODES;                      // 400,000
    int* rank    = hperm + N_EDGES;                     // 400,000

    hipMemsetAsync(cnt, 0, (size_t)(N_NODES + 8) * sizeof(int), stream);

    gemm_kernel<<<(NROWS + 63) / 64, 256, 0, stream>>>(x, W, att, node_idx, hedge_idx,
                                                       xwb, p1, p2, cnt, rank, estart);
    ah_kernel<<<ALLOC_BLOCKS + HEDGE_BLOCKS, 256, 0, stream>>>(cnt, base, gcursor,
                                                               p2, node_idx, estart, s2);
    scatter_kernel<<<(N_EDGES + 255) / 256, 256, 0, stream>>>(node_idx, hedge_idx,
                                                              rank, base, hperm);
    den_kernel<<<(N_NODES + 255) / 256, 256, 0, stream>>>(base, cnt, hperm, p1, s2, den);
    m_kernel<<<HEDGE_BLOCKS, 256, 0, stream>>>(xwb, node_idx, estart, p1, s2, den, m);
    out_kernel<<<(N_NODES + 3) / 4, 256, 0, stream>>>(m, hperm, p1, s2, base, cnt, den, out);
}

// Round 9
// 196.881 us; speedup vs baseline: 3.0199x; 1.0284x over previous
//
#include <hip/hip_runtime.h>
#include <math.h>

#define N_NODES 50000
#define N_HEDGE 5000
#define N_EDGES 400000
#define NB 2
#define NC 64
#define NEG 0.2f
#define NROWS (N_NODES * NB)   // 100000

#define ALLOC_BLOCKS ((N_NODES + 255) / 256)   // 196
#define HEDGE_BLOCKS ((N_HEDGE + 3) / 4)       // 1250

__device__ __forceinline__ unsigned short f2bf(float f) {
    unsigned int u = __float_as_uint(f);
    unsigned int r = (u + 0x7FFFu + ((u >> 16) & 1u)) >> 16;   // RNE
    return (unsigned short)r;
}

__device__ __forceinline__ float lrelu_exp(float r) {
    r = (r >= 0.f) ? r : NEG * r;
    r = fmaxf(r, -80.f);          // denom stays > 0 even pathologically
    return __expf(r);
}

// ---------------- GEMM: xw[row][c] bf16, row = n*2+b; epilogue p1/p2
// fused: incidence count — the atomicAdd return value IS the edge's rank
// within its node's CSR segment (stored to rank[], makes scatter atomic-free)
// + estart binary search.
__global__ __launch_bounds__(256, 4) void gemm_kernel(const float* __restrict__ x,
                                                      const float* __restrict__ W,
                                                      const float* __restrict__ att,
                                                      const int* __restrict__ node_idx,
                                                      const int* __restrict__ hedge_idx,
                                                      unsigned short* __restrict__ xwb,
                                                      float* __restrict__ p1,
                                                      float* __restrict__ p2,
                                                      int* __restrict__ cnt,
                                                      int* __restrict__ rank,
                                                      int* __restrict__ estart)
{
    __shared__ float xs[64 * 68];
    __shared__ float Ws[64 * 68];
    int t = threadIdx.x;
    int R = blockIdx.x * 64;

    // fused count work (grid 1563*256 = 400128 >= N_EDGES, >= N_HEDGE+1)
    int gid = blockIdx.x * 256 + t;
    if (gid < N_EDGES) {
        rank[gid] = atomicAdd(&cnt[node_idx[gid]], 1);
    }
    if (gid <= N_HEDGE) {
        int lo = 0, hi = N_EDGES;
        while (lo < hi) {
            int mid = (lo + hi) >> 1;
            if (hedge_idx[mid] < gid) lo = mid + 1; else hi = mid;
        }
        estart[gid] = lo;
    }

#pragma unroll
    for (int i = 0; i < 4; i++) {
        int lin = t + 256 * i;
        int r = lin >> 4, c4 = lin & 15;
        float4 wv = ((const float4*)W)[lin];
        *(float4*)&Ws[r * 68 + c4 * 4] = wv;
        int g = R + r;
        float4 xv = make_float4(0.f, 0.f, 0.f, 0.f);
        if (g < NROWS) {
            int n = g >> 1, b = g & 1;
            xv = ((const float4*)(x + ((size_t)b * N_NODES + n) * NC))[c4];
        }
        *(float4*)&xs[r * 68 + c4 * 4] = xv;
    }
    __syncthreads();

    int tr = t >> 4, tc = t & 15;
    float acc[4][4];
#pragma unroll
    for (int i = 0; i < 4; i++)
#pragma unroll
        for (int j = 0; j < 4; j++) acc[i][j] = 0.f;

#pragma unroll 4
    for (int k4 = 0; k4 < 16; k4++) {
        float4 xv[4], wv[4];
#pragma unroll
        for (int i = 0; i < 4; i++)
            xv[i] = *(const float4*)&xs[(tr * 4 + i) * 68 + k4 * 4];
#pragma unroll
        for (int kk = 0; kk < 4; kk++)
            wv[kk] = *(const float4*)&Ws[(k4 * 4 + kk) * 68 + tc * 4];
#pragma unroll
        for (int i = 0; i < 4; i++) {
            acc[i][0] = fmaf(xv[i].x, wv[0].x, acc[i][0]);
            acc[i][1] = fmaf(xv[i].x, wv[0].y, acc[i][1]);
            acc[i][2] = fmaf(xv[i].x, wv[0].z, acc[i][2]);
            acc[i][3] = fmaf(xv[i].x, wv[0].w, acc[i][3]);
            acc[i][0] = fmaf(xv[i].y, wv[1].x, acc[i][0]);
            acc[i][1] = fmaf(xv[i].y, wv[1].y, acc[i][1]);
            acc[i][2] = fmaf(xv[i].y, wv[1].z, acc[i][2]);
            acc[i][3] = fmaf(xv[i].y, wv[1].w, acc[i][3]);
            acc[i][0] = fmaf(xv[i].z, wv[2].x, acc[i][0]);
            acc[i][1] = fmaf(xv[i].z, wv[2].y, acc[i][1]);
            acc[i][2] = fmaf(xv[i].z, wv[2].z, acc[i][2]);
            acc[i][3] = fmaf(xv[i].z, wv[2].w, acc[i][3]);
            acc[i][0] = fmaf(xv[i].w, wv[3].x, acc[i][0]);
            acc[i][1] = fmaf(xv[i].w, wv[3].y, acc[i][1]);
            acc[i][2] = fmaf(xv[i].w, wv[3].z, acc[i][2]);
            acc[i][3] = fmaf(xv[i].w, wv[3].w, acc[i][3]);
        }
    }

    float a1x = att[tc * 4], a1y = att[tc * 4 + 1], a1z = att[tc * 4 + 2], a1w = att[tc * 4 + 3];
    float a2x = att[64 + tc * 4], a2y = att[64 + tc * 4 + 1], a2z = att[64 + tc * 4 + 2], a2w = att[64 + tc * 4 + 3];
#pragma unroll
    for (int i = 0; i < 4; i++) {
        int g = R + tr * 4 + i;
        if (g < NROWS) {
            ushort4 bv;
            bv.x = f2bf(acc[i][0]); bv.y = f2bf(acc[i][1]);
            bv.z = f2bf(acc[i][2]); bv.w = f2bf(acc[i][3]);
            ((ushort4*)(xwb + (size_t)g * 64))[tc] = bv;
        }
        float v1 = acc[i][0] * a1x + acc[i][1] * a1y + acc[i][2] * a1z + acc[i][3] * a1w;
        float v2 = acc[i][0] * a2x + acc[i][1] * a2y + acc[i][2] * a2z + acc[i][3] * a2w;
#pragma unroll
        for (int off = 8; off >= 1; off >>= 1) {
            v1 += __shfl_xor(v1, off, 64);
            v2 += __shfl_xor(v2, off, 64);
        }
        if (tc == 0 && g < NROWS) { p1[g] = v1; p2[g] = v2; }
    }
}

// ---------------- fused: segment-base allocator + per-hyperedge p2 sums
// base[n] = segment START (never bumped — scatter is atomic-free via rank[]).
__global__ __launch_bounds__(256) void ah_kernel(const int* __restrict__ cnt,
                                                 int* __restrict__ base,
                                                 int* __restrict__ gcursor,
                                                 const float* __restrict__ p2,
                                                 const int* __restrict__ node_idx,
                                                 const int* __restrict__ estart,
                                                 float* __restrict__ s2)
{
    if (blockIdx.x < ALLOC_BLOCKS) {
        __shared__ int sm[256];
        __shared__ int bbase;
        int tid = threadIdx.x;
        int i = blockIdx.x * 256 + tid;
        int v = (i < N_NODES) ? cnt[i] : 0;
        sm[tid] = v;
        __syncthreads();
        for (int off = 1; off < 256; off <<= 1) {
            int t2 = (tid >= off) ? sm[tid - off] : 0;
            __syncthreads();
            sm[tid] += t2;
            __syncthreads();
        }
        if (tid == 255) bbase = atomicAdd(gcursor, sm[255]);
        __syncthreads();
        if (i < N_NODES) base[i] = bbase + sm[tid] - v;
    } else {
        int wv = (blockIdx.x - ALLOC_BLOCKS) * 4 + (threadIdx.x >> 6);
        if (wv >= N_HEDGE) return;
        int lane = threadIdx.x & 63;
        int s = estart[wv], e1 = estart[wv + 1];
        float a0 = 0.f, a1 = 0.f;
        for (int e = s + lane; e < e1; e += 64) {
            int n = node_idx[e];
            float2 p = ((const float2*)p2)[n];
            a0 += p.x; a1 += p.y;
        }
#pragma unroll
        for (int off = 32; off >= 1; off >>= 1) {
            a0 += __shfl_xor(a0, off, 64);
            a1 += __shfl_xor(a1, off, 64);
        }
        if (lane == 0) { s2[wv * 2] = a0; s2[wv * 2 + 1] = a1; }
    }
}

// ---------------- scatter: atomic-free CSR build.
__global__ __launch_bounds__(256) void scatter_kernel(const int* __restrict__ node_idx,
                                                      const int* __restrict__ hedge_idx,
                                                      const int* __restrict__ rank,
                                                      const int* __restrict__ base,
                                                      int* __restrict__ hperm)
{
    int e = blockIdx.x * 256 + threadIdx.x;
    if (e >= N_EDGES) return;
    int n = node_idx[e];
    hperm[base[n] + rank[e]] = hedge_idx[e];
}

// ---------------- den: per-node (both batches) sum of exp over the CSR segment.
__global__ __launch_bounds__(256) void den_kernel(const int* __restrict__ base,
                                                  const int* __restrict__ cnt,
                                                  const int* __restrict__ hperm,
                                                  const float* __restrict__ p1,
                                                  const float* __restrict__ s2,
                                                  float* __restrict__ den)
{
    int n = blockIdx.x * 256 + threadIdx.x;
    if (n >= N_NODES) return;
    int s = base[n];
    int e1 = s + cnt[n];
    float2 pn = ((const float2*)p1)[n];
    const float2* s2v = (const float2*)s2;
    float a0 = 0.f, a1 = 0.f;
    int j = s;
    for (; j + 3 < e1; j += 4) {   // 4 independent gather chains
        int h0 = hperm[j], h1 = hperm[j + 1], h2 = hperm[j + 2], h3 = hperm[j + 3];
        float2 v0 = s2v[h0], v1 = s2v[h1], v2 = s2v[h2], v3 = s2v[h3];
        a0 += lrelu_exp(pn.x + v0.x) + lrelu_exp(pn.x + v1.x)
            + lrelu_exp(pn.x + v2.x) + lrelu_exp(pn.x + v3.x);
        a1 += lrelu_exp(pn.y + v0.y) + lrelu_exp(pn.y + v1.y)
            + lrelu_exp(pn.y + v2.y) + lrelu_exp(pn.y + v3.y);
    }
    for (; j < e1; j++) {
        float2 v = s2v[hperm[j]];
        a0 += lrelu_exp(pn.x + v.x);
        a1 += lrelu_exp(pn.y + v.y);
    }
    ((float2*)den)[n] = make_float2(a0, a1);
}

// ---------------- pass 1: m[h][k] = (1/deg_h) * sum_{e in h} (ev_e/den[n_e]) * xw[n_e][k]
// R8 PMC: 44us, 13% HBM, 33% VALU, 34% occ -> concurrency-starved latency-bound
// (4 edge-gathers in flight/wave). Fix: 4 waves per hyperedge (1 block each),
// wave w takes edges s+w, s+w+4,...; 4-unrolled -> 16 gathers in flight/hedge;
// 3-slot LDS cross-wave reduce at the end.
__global__ __launch_bounds__(256) void m_kernel(const unsigned short* __restrict__ xwb,
                                                const int* __restrict__ node_idx,
                                                const int* __restrict__ estart,
                                                const float* __restrict__ p1,
                                                const float* __restrict__ s2,
                                                const float* __restrict__ den,
                                                float* __restrict__ m)
{
    __shared__ float red[3][128];
    int h = blockIdx.x;
    int t = threadIdx.x;
    int w = t >> 6, l = t & 63;
    int b = l >> 5;                       // channel 2l: b = (2l)>>6
    int s = estart[h], e1 = estart[h + 1];
    float2 s2h = ((const float2*)s2)[h];  // block-uniform
    float sb = b ? s2h.y : s2h.x;
    const float2* p1v = (const float2*)p1;
    const float2* dn2 = (const float2*)den;
    float ax = 0.f, ay = 0.f;
    int e = s + w;                        // wave-strided edges (stride 4)
    for (; e + 12 < e1; e += 16) {
        int n0 = node_idx[e],     n1 = node_idx[e + 4];
        int n2 = node_idx[e + 8], n3 = node_idx[e + 12];
        float2 q0 = p1v[n0], q1 = p1v[n1], q2 = p1v[n2], q3 = p1v[n3];
        float2 d0 = dn2[n0], d1 = dn2[n1], d2 = dn2[n2], d3 = dn2[n3];
        float a0 = lrelu_exp((b ? q0.y : q0.x) + sb) * __builtin_amdgcn_rcpf(b ? d0.y : d0.x);
        float a1 = lrelu_exp((b ? q1.y : q1.x) + sb) * __builtin_amdgcn_rcpf(b ? d1.y : d1.x);
        float a2 = lrelu_exp((b ? q2.y : q2.x) + sb) * __builtin_amdgcn_rcpf(b ? d2.y : d2.x);
        float a3 = lrelu_exp((b ? q3.y : q3.x) + sb) * __builtin_amdgcn_rcpf(b ? d3.y : d3.x);
        unsigned int u0 = *(const unsigned int*)&xwb[(size_t)n0 * 128 + 2 * l];
        unsigned int u1 = *(const unsigned int*)&xwb[(size_t)n1 * 128 + 2 * l];
        unsigned int u2 = *(const unsigned int*)&xwb[(size_t)n2 * 128 + 2 * l];
        unsigned int u3 = *(const unsigned int*)&xwb[(size_t)n3 * 128 + 2 * l];
        ax = fmaf(a0, __uint_as_float(u0 << 16), ax);
        ay = fmaf(a0, __uint_as_float(u0 & 0xffff0000u), ay);
        ax = fmaf(a1, __uint_as_float(u1 << 16), ax);
        ay = fmaf(a1, __uint_as_float(u1 & 0xffff0000u), ay);
        ax = fmaf(a2, __uint_as_float(u2 << 16), ax);
        ay = fmaf(a2, __uint_as_float(u2 & 0xffff0000u), ay);
        ax = fmaf(a3, __uint_as_float(u3 << 16), ax);
        ay = fmaf(a3, __uint_as_float(u3 & 0xffff0000u), ay);
    }
    for (; e < e1; e += 4) {
        int n = node_idx[e];
        float2 q = p1v[n];
        float2 dv = dn2[n];
        float a0 = lrelu_exp((b ? q.y : q.x) + sb) * __builtin_amdgcn_rcpf(b ? dv.y : dv.x);
        unsigned int u = *(const unsigned int*)&xwb[(size_t)n * 128 + 2 * l];
        ax = fmaf(a0, __uint_as_float(u << 16), ax);
        ay = fmaf(a0, __uint_as_float(u & 0xffff0000u), ay);
    }
    if (w) { red[w - 1][2 * l] = ax; red[w - 1][2 * l + 1] = ay; }
    __syncthreads();
    if (w == 0) {
        ax += red[0][2 * l] + red[1][2 * l] + red[2][2 * l];
        ay += red[0][2 * l + 1] + red[1][2 * l + 1] + red[2][2 * l + 1];
        int d = e1 - s;
        float binv = (d > 0) ? 1.0f / (float)d : 0.0f;
        ((float2*)(m + (size_t)h * 128))[l] = make_float2(binv * ax, binv * ay);
    }
}

// ---------------- pass 2: out[b][n][c] = (deg/den[n]) * sum_j ev_j * m[h_j][k]
// 1 wave per node; ev recomputed inline (p1[2n+b] half-wave-uniform, s2[h]
// gather broadcasts within each half-wave).
__global__ __launch_bounds__(256) void out_kernel(const float* __restrict__ m,
                                                  const int* __restrict__ hperm,
                                                  const float* __restrict__ p1,
                                                  const float* __restrict__ s2,
                                                  const int* __restrict__ base,
                                                  const int* __restrict__ cnt,
                                                  const float* __restrict__ den,
                                                  float* __restrict__ out)
{
    int n = blockIdx.x * 4 + (threadIdx.x >> 6);
    if (n >= N_NODES) return;
    int l = threadIdx.x & 63;
    int b = l >> 5;
    int d = cnt[n];
    int s = base[n];
    int e1 = s + d;
    float pnb = p1[2 * n + b];
    const float2* s2v = (const float2*)s2;
    float ax = 0.f, ay = 0.f;
    int j = s;
    for (; j + 3 < e1; j += 4) {
        int h0 = hperm[j],     h1 = hperm[j + 1];
        int h2 = hperm[j + 2], h3 = hperm[j + 3];
        float2 w0 = s2v[h0], w1 = s2v[h1], w2 = s2v[h2], w3 = s2v[h3];
        float a0 = lrelu_exp(pnb + (b ? w0.y : w0.x));
        float a1 = lrelu_exp(pnb + (b ? w1.y : w1.x));
        float a2 = lrelu_exp(pnb + (b ? w2.y : w2.x));
        float a3 = lrelu_exp(pnb + (b ? w3.y : w3.x));
        float2 v0 = ((const float2*)(m + (size_t)h0 * 128))[l];
        float2 v1 = ((const float2*)(m + (size_t)h1 * 128))[l];
        float2 v2 = ((const float2*)(m + (size_t)h2 * 128))[l];
        float2 v3 = ((const float2*)(m + (size_t)h3 * 128))[l];
        ax = fmaf(a0, v0.x, ax); ay = fmaf(a0, v0.y, ay);
        ax = fmaf(a1, v1.x, ax); ay = fmaf(a1, v1.y, ay);
        ax = fmaf(a2, v2.x, ax); ay = fmaf(a2, v2.y, ay);
        ax = fmaf(a3, v3.x, ax); ay = fmaf(a3, v3.y, ay);
    }
    for (; j < e1; j++) {
        int h = hperm[j];
        float2 w0 = s2v[h];
        float a0 = lrelu_exp(pnb + (b ? w0.y : w0.x));
        float2 v = ((const float2*)(m + (size_t)h * 128))[l];
        ax = fmaf(a0, v.x, ax); ay = fmaf(a0, v.y, ay);
    }
    float dd = den[2 * n + b];
    // deg * (1/den); zero-degree nodes write exact 0 (ax=ay=0, scale=0)
    float scale = (d > 0) ? (float)d * __builtin_amdgcn_rcpf(dd) : 0.f;
    int c = (2 * l) & 63;
    float* dst = out + (size_t)b * N_NODES * 64 + (size_t)n * 64 + c;
    __builtin_nontemporal_store(scale * ax, &dst[0]);
    __builtin_nontemporal_store(scale * ay, &dst[1]);
}

extern "C" void kernel_launch(void* const* d_in, const int* in_sizes, int n_in,
                              void* d_out, int out_size, void* d_ws, size_t ws_size,
                              hipStream_t stream)
{
    const float* x      = (const float*)d_in[0];
    const float* W      = (const float*)d_in[1];
    const float* att    = (const float*)d_in[2];
    const int* node_idx = (const int*)d_in[3];
    const int* hedge_idx= (const int*)d_in[4];
    float* out = (float*)d_out;

    // workspace layout — ~23MB total
    unsigned short* xwb = (unsigned short*)d_ws;        // 6,400,000 ushort (12.8MB)
    float* p1     = (float*)(xwb + (size_t)NROWS * NC); // 100,000
    float* p2     = p1 + NROWS;                         // 100,000
    float* s2     = p2 + NROWS;                         // 10,000
    float* m      = s2 + 10000;                         // 640,000
    float* den    = m + (size_t)N_HEDGE * NB * NC;      // 100,000
    int* estart  = (int*)(den + NROWS);                 // 5,008 (padded)
    int* cnt     = estart + 5008;                       // 50,000 ┐ contiguous memset
    int* gcursor = cnt + N_NODES;                       // 8      ┘
    int* base    = gcursor + 8;                         // 50,000
    int* hperm   = base + N_NODES;                      // 400,000
    int* rank    = hperm + N_EDGES;                     // 400,000

    hipMemsetAsync(cnt, 0, (size_t)(N_NODES + 8) * sizeof(int), stream);

    gemm_kernel<<<(NROWS + 63) / 64, 256, 0, stream>>>(x, W, att, node_idx, hedge_idx,
                                                       xwb, p1, p2, cnt, rank, estart);
    ah_kernel<<<ALLOC_BLOCKS + HEDGE_BLOCKS, 256, 0, stream>>>(cnt, base, gcursor,
                                                               p2, node_idx, estart, s2);
    scatter_kernel<<<(N_EDGES + 255) / 256, 256, 0, stream>>>(node_idx, hedge_idx,
                                                              rank, base, hperm);
    den_kernel<<<(N_NODES + 255) / 256, 256, 0, stream>>>(base, cnt, hperm, p1, s2, den);
    m_kernel<<<N_HEDGE, 256, 0, stream>>>(xwb, node_idx, estart, p1, s2, den, m);
    out_kernel<<<(N_NODES + 3) / 4, 256, 0, stream>>>(m, hperm, p1, s2, base, cnt, den, out);
}